// Round 1
// baseline (1426.291 us; speedup 1.0000x reference)
//
#include <hip/hip_runtime.h>
#include <cstdint>
#include <cstddef>

#define TOKENS 1024
#define DMODEL 2048
#define NEXP   64
#define FDIM   768
#define CAP    256   // max tokens per expert (mean 128, sigma ~11 -> 11 sigma headroom)
#define TOPK   8

typedef __bf16 bf16;
typedef __bf16 bf16x8 __attribute__((ext_vector_type(8)));
typedef float  f32x4  __attribute__((ext_vector_type(4)));

// async global->LDS, 16B per lane; LDS dest = wave-uniform base + lane*16
__device__ __forceinline__ void g2lds16(const void* g, void* l) {
  __builtin_amdgcn_global_load_lds(
      (const __attribute__((address_space(1))) uint32_t*)g,
      (__attribute__((address_space(3))) uint32_t*)l, 16, 0, 0);
}

// ---------------------------------------------------------------------------
// Router: fp32 logits, top-8 (lowest-index tie-break), renormalized weights,
// scatter into per-expert token lists.
// ---------------------------------------------------------------------------
__global__ void router_kernel(const float* __restrict__ x,
                              const float* __restrict__ gw,
                              int* __restrict__ cnt,
                              int* __restrict__ ltok,
                              float* __restrict__ lwt) {
  const int t = blockIdx.x;
  const int tid = threadIdx.x;
  __shared__ float xs[DMODEL];
  __shared__ float part[256];
  {
    const float4* src = (const float4*)(x + (size_t)t * DMODEL);
    float4* dst = (float4*)xs;
    for (int c = tid; c < DMODEL / 4; c += 256) dst[c] = src[c];
  }
  __syncthreads();
  {
    const int e = tid & 63, seg = tid >> 6;
    const float4* xa = (const float4*)xs + seg * 128;
    const float4* wa = (const float4*)(gw + (size_t)e * DMODEL + seg * 512);
    float acc = 0.f;
#pragma unroll 8
    for (int i = 0; i < 128; i++) {
      float4 a = xa[i], b = wa[i];
      acc += a.x * b.x + a.y * b.y + a.z * b.z + a.w * b.w;
    }
    part[tid] = acc;
  }
  __syncthreads();
  if (tid < 64) {
    float l = part[tid] + part[tid + 64] + part[tid + 128] + part[tid + 192];
    float m0 = 0.f, wsum = 0.f, myw = 0.f;
    int mye = 0;
#pragma unroll
    for (int k = 0; k < TOPK; k++) {
      float m = l;
#pragma unroll
      for (int off = 32; off > 0; off >>= 1) m = fmaxf(m, __shfl_xor(m, off));
      unsigned long long bal = __ballot(l == m);
      int ln = __ffsll(bal) - 1;          // lowest lane on tie = numpy order
      if (k == 0) m0 = m;
      float wk = expf(m - m0);            // Z cancels in renorm
      wsum += wk;
      if (tid == k) { mye = ln; myw = wk; }
      if (tid == ln) l = -3.0e38f;
    }
    if (tid < TOPK) {
      float wfin = myw / wsum;
      int pos = atomicAdd(cnt + mye, 1);
      if (pos < CAP) {
        ltok[mye * CAP + pos] = t;
        lwt[mye * CAP + pos]  = wfin;
      }
    }
  }
}

// ---------------------------------------------------------------------------
// Gather routed token rows into per-expert bf16 matrices Xg[e][CAP][DMODEL]
// ---------------------------------------------------------------------------
__global__ void gather_kernel(const float* __restrict__ x,
                              const int* __restrict__ cnt,
                              const int* __restrict__ ltok,
                              bf16* __restrict__ Xg) {
  const int e = blockIdx.y;
  int n_e = cnt[e]; if (n_e > CAP) n_e = CAP;
  const int r0 = blockIdx.x * 32;
  const int tid = threadIdx.x;
  const int rend = (r0 + 32 < n_e) ? r0 + 32 : n_e;
  for (int r = r0; r < rend; r++) {
    const int tok = ltok[e * CAP + r];
    const float4* src = (const float4*)(x + (size_t)tok * DMODEL);
    bf16* dst = Xg + ((size_t)e * CAP + r) * DMODEL;
    for (int c = tid; c < DMODEL / 4; c += 256) {
      float4 v = src[c];
      union { bf16 h[4]; uint2 u; } pk;
      pk.h[0] = (bf16)v.x; pk.h[1] = (bf16)v.y;
      pk.h[2] = (bf16)v.z; pk.h[3] = (bf16)v.w;
      *(uint2*)(dst + 4 * c) = pk.u;
    }
  }
}

// ---------------------------------------------------------------------------
// GEMM1: H = silu(Xg @ Wg^T) * (Xg @ Wu^T)  per expert.
// Block: (expert, n-tile of 32 H-cols). BM=256 (whole expert), BK=64.
// B tile = 32 gate rows + 32 up rows of w13 (fp32 -> bf16 in staging).
// 16-row subtiles round-robined across 4 waves; inactive subtiles skipped.
// ---------------------------------------------------------------------------
__global__ __launch_bounds__(256, 2)
void gemm1_kernel(const float* __restrict__ w13,
                  const bf16* __restrict__ Xg,
                  const int* __restrict__ cnt,
                  bf16* __restrict__ H) {
  const int e = blockIdx.y;
  int n_e = cnt[e]; if (n_e > CAP) n_e = CAP;
  if (n_e <= 0) return;
  const int nt = blockIdx.x;                 // H cols [nt*32, nt*32+32)
  const int tid = threadIdx.x;
  const int wave = tid >> 6, lane = tid & 63;
  const int lm = lane & 15, lq = lane >> 4;
  const int M_act = (n_e + 15) & ~15;

  __shared__ bf16 As[CAP * 64];              // 32 KB
  __shared__ bf16 Bs[64 * 64];               // 8 KB

  f32x4 acc[4][4];
#pragma unroll
  for (int a = 0; a < 4; a++)
#pragma unroll
    for (int b = 0; b < 4; b++) acc[a][b] = (f32x4){0.f, 0.f, 0.f, 0.f};

  int rowb[4]; bool ract[4];
#pragma unroll
  for (int rf = 0; rf < 4; rf++) {
    rowb[rf] = (rf * 4 + wave) * 16;         // interleave -> load balance
    ract[rf] = rowb[rf] < n_e;
  }

  const int bj = tid >> 2, bq = tid & 3;     // B-tile row 0..63, quarter
  const size_t wrow = (bj < 32) ? (size_t)(nt * 32 + bj)
                                : (size_t)(FDIM + nt * 32 + (bj - 32));
  const float* bsrc = w13 + ((size_t)e * (2 * FDIM) + wrow) * DMODEL + bq * 16;
  const bf16* abase = Xg + (size_t)e * CAP * DMODEL
                      + (size_t)(lane >> 3) * DMODEL + (lane & 7) * 8;

  for (int k0 = 0; k0 < DMODEL; k0 += 64) {
    // stage A (bf16, direct-to-LDS, 8 rows / issue, active rows only)
    for (int i = wave; i * 8 < M_act; i += 4)
      g2lds16(abase + (size_t)i * 8 * DMODEL + k0, &As[i * 512]);
    // stage B (fp32 -> bf16 via VGPR)
    {
      const float* s = bsrc + k0;
      float4 f0 = *(const float4*)(s);
      float4 f1 = *(const float4*)(s + 4);
      float4 f2 = *(const float4*)(s + 8);
      float4 f3 = *(const float4*)(s + 12);
      union { bf16 h[16]; uint4 u[2]; } pk;
      pk.h[0]=(bf16)f0.x; pk.h[1]=(bf16)f0.y; pk.h[2]=(bf16)f0.z; pk.h[3]=(bf16)f0.w;
      pk.h[4]=(bf16)f1.x; pk.h[5]=(bf16)f1.y; pk.h[6]=(bf16)f1.z; pk.h[7]=(bf16)f1.w;
      pk.h[8]=(bf16)f2.x; pk.h[9]=(bf16)f2.y; pk.h[10]=(bf16)f2.z; pk.h[11]=(bf16)f2.w;
      pk.h[12]=(bf16)f3.x; pk.h[13]=(bf16)f3.y; pk.h[14]=(bf16)f3.z; pk.h[15]=(bf16)f3.w;
      uint4* bd = (uint4*)&Bs[bj * 64 + bq * 16];
      bd[0] = pk.u[0]; bd[1] = pk.u[1];
    }
    __syncthreads();
#pragma unroll
    for (int ks = 0; ks < 2; ks++) {
      bf16x8 bfr[4];
#pragma unroll
      for (int cf = 0; cf < 4; cf++)
        bfr[cf] = *(const bf16x8*)&Bs[(cf * 16 + lm) * 64 + ks * 32 + lq * 8];
#pragma unroll
      for (int rf = 0; rf < 4; rf++) {
        if (ract[rf]) {
          bf16x8 afr = *(const bf16x8*)&As[(rowb[rf] + lm) * 64 + ks * 32 + lq * 8];
#pragma unroll
          for (int cf = 0; cf < 4; cf++)
            acc[rf][cf] = __builtin_amdgcn_mfma_f32_16x16x32_bf16(
                afr, bfr[cf], acc[rf][cf], 0, 0, 0);
        }
      }
    }
    __syncthreads();
  }

  // epilogue: cols 0-31 = gate, 32-63 = up (same lane holds both) -> SwiGLU
#pragma unroll
  for (int rf = 0; rf < 4; rf++) {
    if (!ract[rf]) continue;
#pragma unroll
    for (int cf = 0; cf < 2; cf++) {
      const int hcol = nt * 32 + cf * 16 + lm;
#pragma unroll
      for (int i = 0; i < 4; i++) {
        const int r = rowb[rf] + lq * 4 + i;
        if (r < n_e) {
          float g = acc[rf][cf][i];
          float u = acc[rf][cf + 2][i];
          float s = g / (1.f + __expf(-g));
          H[((size_t)e * CAP + r) * FDIM + hcol] = (bf16)(s * u);
        }
      }
    }
  }
}

// ---------------------------------------------------------------------------
// GEMM2: out[tok] += w * (H @ W2^T). Block: (expert, 64 D-cols). K=768.
// ---------------------------------------------------------------------------
__global__ __launch_bounds__(256, 2)
void gemm2_kernel(const float* __restrict__ w2,
                  const bf16* __restrict__ H,
                  const int* __restrict__ cnt,
                  const int* __restrict__ ltok,
                  const float* __restrict__ lwt,
                  float* __restrict__ out) {
  const int e = blockIdx.y;
  int n_e = cnt[e]; if (n_e > CAP) n_e = CAP;
  if (n_e <= 0) return;
  const int nt = blockIdx.x;                 // D cols [nt*64, nt*64+64)
  const int tid = threadIdx.x;
  const int wave = tid >> 6, lane = tid & 63;
  const int lm = lane & 15, lq = lane >> 4;
  const int M_act = (n_e + 15) & ~15;

  __shared__ bf16 As[CAP * 64];
  __shared__ bf16 Bs[64 * 64];

  f32x4 acc[4][4];
#pragma unroll
  for (int a = 0; a < 4; a++)
#pragma unroll
    for (int b = 0; b < 4; b++) acc[a][b] = (f32x4){0.f, 0.f, 0.f, 0.f};

  int rowb[4]; bool ract[4];
#pragma unroll
  for (int rf = 0; rf < 4; rf++) {
    rowb[rf] = (rf * 4 + wave) * 16;
    ract[rf] = rowb[rf] < n_e;
  }

  const int bj = tid >> 2, bq = tid & 3;
  const float* bsrc = w2 + ((size_t)e * DMODEL + nt * 64 + bj) * FDIM + bq * 16;
  const bf16* abase = H + (size_t)e * CAP * FDIM
                      + (size_t)(lane >> 3) * FDIM + (lane & 7) * 8;

  for (int k0 = 0; k0 < FDIM; k0 += 64) {
    for (int i = wave; i * 8 < M_act; i += 4)
      g2lds16(abase + (size_t)i * 8 * FDIM + k0, &As[i * 512]);
    {
      const float* s = bsrc + k0;
      float4 f0 = *(const float4*)(s);
      float4 f1 = *(const float4*)(s + 4);
      float4 f2 = *(const float4*)(s + 8);
      float4 f3 = *(const float4*)(s + 12);
      union { bf16 h[16]; uint4 u[2]; } pk;
      pk.h[0]=(bf16)f0.x; pk.h[1]=(bf16)f0.y; pk.h[2]=(bf16)f0.z; pk.h[3]=(bf16)f0.w;
      pk.h[4]=(bf16)f1.x; pk.h[5]=(bf16)f1.y; pk.h[6]=(bf16)f1.z; pk.h[7]=(bf16)f1.w;
      pk.h[8]=(bf16)f2.x; pk.h[9]=(bf16)f2.y; pk.h[10]=(bf16)f2.z; pk.h[11]=(bf16)f2.w;
      pk.h[12]=(bf16)f3.x; pk.h[13]=(bf16)f3.y; pk.h[14]=(bf16)f3.z; pk.h[15]=(bf16)f3.w;
      uint4* bd = (uint4*)&Bs[bj * 64 + bq * 16];
      bd[0] = pk.u[0]; bd[1] = pk.u[1];
    }
    __syncthreads();
#pragma unroll
    for (int ks = 0; ks < 2; ks++) {
      bf16x8 bfr[4];
#pragma unroll
      for (int cf = 0; cf < 4; cf++)
        bfr[cf] = *(const bf16x8*)&Bs[(cf * 16 + lm) * 64 + ks * 32 + lq * 8];
#pragma unroll
      for (int rf = 0; rf < 4; rf++) {
        if (ract[rf]) {
          bf16x8 afr = *(const bf16x8*)&As[(rowb[rf] + lm) * 64 + ks * 32 + lq * 8];
#pragma unroll
          for (int cf = 0; cf < 4; cf++)
            acc[rf][cf] = __builtin_amdgcn_mfma_f32_16x16x32_bf16(
                afr, bfr[cf], acc[rf][cf], 0, 0, 0);
        }
      }
    }
    __syncthreads();
  }

  // epilogue: weighted scatter-add into out
#pragma unroll
  for (int rf = 0; rf < 4; rf++) {
    if (!ract[rf]) continue;
#pragma unroll
    for (int i = 0; i < 4; i++) {
      const int r = rowb[rf] + lq * 4 + i;
      if (r < n_e) {
        const int tok = ltok[e * CAP + r];
        const float cw = lwt[e * CAP + r];
        float* orow = out + (size_t)tok * DMODEL + nt * 64 + lm;
#pragma unroll
        for (int cf = 0; cf < 4; cf++)
          atomicAdd(orow + cf * 16, cw * acc[rf][cf][i]);
      }
    }
  }
}

// ---------------------------------------------------------------------------
extern "C" void kernel_launch(void* const* d_in, const int* in_sizes, int n_in,
                              void* d_out, int out_size, void* d_ws, size_t ws_size,
                              hipStream_t stream) {
  const float* x      = (const float*)d_in[0];   // [1024, 2048]
  const float* gate_w = (const float*)d_in[1];   // [64, 2048]
  const float* w13    = (const float*)d_in[2];   // [64, 1536, 2048]
  const float* w2     = (const float*)d_in[3];   // [64, 2048, 768]
  float* out = (float*)d_out;

  char* ws = (char*)d_ws;
  int*   cnt  = (int*)ws;                                   // 256 B
  int*   ltok = (int*)(ws + 1024);                          // 64 KB
  float* lwt  = (float*)(ws + 1024 + 65536);                // 64 KB
  bf16*  Xg   = (bf16*)(ws + 1024 + 2 * 65536);             // 64 MB
  bf16*  H    = (bf16*)(ws + 1024 + 2 * 65536
                        + (size_t)NEXP * CAP * DMODEL * sizeof(bf16)); // 24 MB

  hipMemsetAsync(d_out, 0, (size_t)out_size * sizeof(float), stream);
  hipMemsetAsync(cnt, 0, NEXP * sizeof(int), stream);

  router_kernel<<<TOKENS, 256, 0, stream>>>(x, gate_w, cnt, ltok, lwt);
  gather_kernel<<<dim3(CAP / 32, NEXP), 256, 0, stream>>>(x, cnt, ltok, Xg);
  gemm1_kernel<<<dim3(FDIM / 32, NEXP), 256, 0, stream>>>(w13, Xg, cnt, H);
  gemm2_kernel<<<dim3(DMODEL / 64, NEXP), 256, 0, stream>>>(w2, H, cnt, ltok, lwt, out);
}

// Round 2
// 1406.899 us; speedup vs baseline: 1.0138x; 1.0138x over previous
//
#include <hip/hip_runtime.h>
#include <cstdint>
#include <cstddef>

#define TOKENS 1024
#define DMODEL 2048
#define NEXP   64
#define FDIM   768
#define CAP    256   // max tokens per expert (mean 128, sigma ~11 -> 11 sigma headroom)
#define TOPK   8

typedef __bf16 bf16;
typedef __bf16 bf16x8 __attribute__((ext_vector_type(8)));
typedef float  f32x4  __attribute__((ext_vector_type(4)));

// async global->LDS, 16B per lane; LDS dest = wave-uniform base + lane*16
__device__ __forceinline__ void g2lds16(const void* g, void* l) {
  __builtin_amdgcn_global_load_lds(
      (const __attribute__((address_space(1))) uint32_t*)g,
      (__attribute__((address_space(3))) uint32_t*)l, 16, 0, 0);
}

// ---------------------------------------------------------------------------
// Router: fp32 logits, top-8 (lowest-index tie-break), renormalized weights,
// scatter into per-expert token lists.
// ---------------------------------------------------------------------------
__global__ void router_kernel(const float* __restrict__ x,
                              const float* __restrict__ gw,
                              int* __restrict__ cnt,
                              int* __restrict__ ltok,
                              float* __restrict__ lwt) {
  const int t = blockIdx.x;
  const int tid = threadIdx.x;
  __shared__ float xs[DMODEL];
  __shared__ float part[256];
  {
    const float4* src = (const float4*)(x + (size_t)t * DMODEL);
    float4* dst = (float4*)xs;
    for (int c = tid; c < DMODEL / 4; c += 256) dst[c] = src[c];
  }
  __syncthreads();
  {
    const int e = tid & 63, seg = tid >> 6;
    const float4* xa = (const float4*)xs + seg * 128;
    const float4* wa = (const float4*)(gw + (size_t)e * DMODEL + seg * 512);
    float acc = 0.f;
#pragma unroll 8
    for (int i = 0; i < 128; i++) {
      float4 a = xa[i], b = wa[i];
      acc += a.x * b.x + a.y * b.y + a.z * b.z + a.w * b.w;
    }
    part[tid] = acc;
  }
  __syncthreads();
  if (tid < 64) {
    float l = part[tid] + part[tid + 64] + part[tid + 128] + part[tid + 192];
    float m0 = 0.f, wsum = 0.f, myw = 0.f;
    int mye = 0;
#pragma unroll
    for (int k = 0; k < TOPK; k++) {
      float m = l;
#pragma unroll
      for (int off = 32; off > 0; off >>= 1) m = fmaxf(m, __shfl_xor(m, off));
      unsigned long long bal = __ballot(l == m);
      int ln = __ffsll(bal) - 1;          // lowest lane on tie = numpy order
      if (k == 0) m0 = m;
      float wk = expf(m - m0);            // Z cancels in renorm
      wsum += wk;
      if (tid == k) { mye = ln; myw = wk; }
      if (tid == ln) l = -3.0e38f;
    }
    if (tid < TOPK) {
      float wfin = myw / wsum;
      int pos = atomicAdd(cnt + mye, 1);
      if (pos < CAP) {
        ltok[mye * CAP + pos] = t;
        lwt[mye * CAP + pos]  = wfin;
      }
    }
  }
}

// ---------------------------------------------------------------------------
// Gather routed token rows into per-expert bf16 matrices Xg[e][CAP][DMODEL]
// ---------------------------------------------------------------------------
__global__ void gather_kernel(const float* __restrict__ x,
                              const int* __restrict__ cnt,
                              const int* __restrict__ ltok,
                              bf16* __restrict__ Xg) {
  const int e = blockIdx.y;
  int n_e = cnt[e]; if (n_e > CAP) n_e = CAP;
  const int r0 = blockIdx.x * 32;
  const int tid = threadIdx.x;
  const int rend = (r0 + 32 < n_e) ? r0 + 32 : n_e;
  for (int r = r0; r < rend; r++) {
    const int tok = ltok[e * CAP + r];
    const float4* src = (const float4*)(x + (size_t)tok * DMODEL);
    bf16* dst = Xg + ((size_t)e * CAP + r) * DMODEL;
    for (int c = tid; c < DMODEL / 4; c += 256) {
      float4 v = src[c];
      union { bf16 h[4]; uint2 u; } pk;
      pk.h[0] = (bf16)v.x; pk.h[1] = (bf16)v.y;
      pk.h[2] = (bf16)v.z; pk.h[3] = (bf16)v.w;
      *(uint2*)(dst + 4 * c) = pk.u;
    }
  }
}

// ---------------------------------------------------------------------------
// GEMM1: H = silu(Xg @ Wg^T) * (Xg @ Wu^T)  per expert.
// LDS layout XOR-swizzled: row r, 16B-chunk c stored at chunk c^(r&7).
//   -> fragment ds_read_b128 goes from 16-way bank conflict to 2-way (free).
// A is staged with global_load_lds (contiguous LDS dest), so the swizzle is
// applied on the GLOBAL source address per lane instead (row&7 is invariant
// across the 8-row issues).
// ---------------------------------------------------------------------------
__global__ __launch_bounds__(256, 2)
void gemm1_kernel(const float* __restrict__ w13,
                  const bf16* __restrict__ Xg,
                  const int* __restrict__ cnt,
                  bf16* __restrict__ H) {
  const int e = blockIdx.y;
  int n_e = cnt[e]; if (n_e > CAP) n_e = CAP;
  if (n_e <= 0) return;
  const int nt = blockIdx.x;                 // H cols [nt*32, nt*32+32)
  const int tid = threadIdx.x;
  const int wave = tid >> 6, lane = tid & 63;
  const int lm = lane & 15, lq = lane >> 4;
  const int M_act = (n_e + 15) & ~15;

  __shared__ bf16 As[CAP * 64];              // 32 KB
  __shared__ bf16 Bs[64 * 64];               // 8 KB

  f32x4 acc[4][4];
#pragma unroll
  for (int a = 0; a < 4; a++)
#pragma unroll
    for (int b = 0; b < 4; b++) acc[a][b] = (f32x4){0.f, 0.f, 0.f, 0.f};

  int rowb[4]; bool ract[4];
#pragma unroll
  for (int rf = 0; rf < 4; rf++) {
    rowb[rf] = (rf * 4 + wave) * 16;         // interleave -> load balance
    ract[rf] = rowb[rf] < n_e;
  }

  const int bj = tid >> 2, bq = tid & 3;     // B-tile row 0..63, quarter
  const size_t wrow = (bj < 32) ? (size_t)(nt * 32 + bj)
                                : (size_t)(FDIM + nt * 32 + (bj - 32));
  const float* bsrc = w13 + ((size_t)e * (2 * FDIM) + wrow) * DMODEL + bq * 16;
  // A source: lane fetches swizzled global chunk so LDS slot (r, c) holds
  // global chunk c^(r&7)
  const int arow = lane >> 3;
  const int achk = (lane & 7) ^ (arow & 7);
  const bf16* abase = Xg + (size_t)e * CAP * DMODEL
                      + (size_t)arow * DMODEL + achk * 8;

  for (int k0 = 0; k0 < DMODEL; k0 += 64) {
    // stage A (bf16, direct-to-LDS, 8 rows / issue, active rows only)
    for (int i = wave; i * 8 < M_act; i += 4)
      g2lds16(abase + (size_t)i * 8 * DMODEL + k0, &As[i * 512]);
    // stage B (fp32 -> bf16 via VGPR), swizzled write
    {
      const float* s = bsrc + k0;
      float4 f0 = *(const float4*)(s);
      float4 f1 = *(const float4*)(s + 4);
      float4 f2 = *(const float4*)(s + 8);
      float4 f3 = *(const float4*)(s + 12);
      union { bf16 h[16]; uint4 u[2]; } pk;
      pk.h[0]=(bf16)f0.x; pk.h[1]=(bf16)f0.y; pk.h[2]=(bf16)f0.z; pk.h[3]=(bf16)f0.w;
      pk.h[4]=(bf16)f1.x; pk.h[5]=(bf16)f1.y; pk.h[6]=(bf16)f1.z; pk.h[7]=(bf16)f1.w;
      pk.h[8]=(bf16)f2.x; pk.h[9]=(bf16)f2.y; pk.h[10]=(bf16)f2.z; pk.h[11]=(bf16)f2.w;
      pk.h[12]=(bf16)f3.x; pk.h[13]=(bf16)f3.y; pk.h[14]=(bf16)f3.z; pk.h[15]=(bf16)f3.w;
      const int c0 = (bq * 2) ^ (bj & 7);
      const int c1 = (bq * 2 + 1) ^ (bj & 7);
      *(uint4*)&Bs[bj * 64 + c0 * 8] = pk.u[0];
      *(uint4*)&Bs[bj * 64 + c1 * 8] = pk.u[1];
    }
    __syncthreads();
#pragma unroll
    for (int ks = 0; ks < 2; ks++) {
      const int sw = ((ks * 4 + lq) ^ (lm & 7)) * 8;   // swizzled chunk offset
      bf16x8 bfr[4];
#pragma unroll
      for (int cf = 0; cf < 4; cf++)
        bfr[cf] = *(const bf16x8*)&Bs[(cf * 16 + lm) * 64 + sw];
#pragma unroll
      for (int rf = 0; rf < 4; rf++) {
        if (ract[rf]) {
          bf16x8 afr = *(const bf16x8*)&As[(rowb[rf] + lm) * 64 + sw];
#pragma unroll
          for (int cf = 0; cf < 4; cf++)
            acc[rf][cf] = __builtin_amdgcn_mfma_f32_16x16x32_bf16(
                afr, bfr[cf], acc[rf][cf], 0, 0, 0);
        }
      }
    }
    __syncthreads();
  }

  // epilogue: cols 0-31 = gate, 32-63 = up (same lane holds both) -> SwiGLU
#pragma unroll
  for (int rf = 0; rf < 4; rf++) {
    if (!ract[rf]) continue;
#pragma unroll
    for (int cf = 0; cf < 2; cf++) {
      const int hcol = nt * 32 + cf * 16 + lm;
#pragma unroll
      for (int i = 0; i < 4; i++) {
        const int r = rowb[rf] + lq * 4 + i;
        if (r < n_e) {
          float g = acc[rf][cf][i];
          float u = acc[rf][cf + 2][i];
          float s = g / (1.f + __expf(-g));
          H[((size_t)e * CAP + r) * FDIM + hcol] = (bf16)(s * u);
        }
      }
    }
  }
}

// ---------------------------------------------------------------------------
// GEMM2: out[tok] += w * (H @ W2^T). Block: (expert, 64 D-cols). K=768.
// Same XOR swizzle as gemm1.
// ---------------------------------------------------------------------------
__global__ __launch_bounds__(256, 2)
void gemm2_kernel(const float* __restrict__ w2,
                  const bf16* __restrict__ H,
                  const int* __restrict__ cnt,
                  const int* __restrict__ ltok,
                  const float* __restrict__ lwt,
                  float* __restrict__ out) {
  const int e = blockIdx.y;
  int n_e = cnt[e]; if (n_e > CAP) n_e = CAP;
  if (n_e <= 0) return;
  const int nt = blockIdx.x;                 // D cols [nt*64, nt*64+64)
  const int tid = threadIdx.x;
  const int wave = tid >> 6, lane = tid & 63;
  const int lm = lane & 15, lq = lane >> 4;
  const int M_act = (n_e + 15) & ~15;

  __shared__ bf16 As[CAP * 64];
  __shared__ bf16 Bs[64 * 64];

  f32x4 acc[4][4];
#pragma unroll
  for (int a = 0; a < 4; a++)
#pragma unroll
    for (int b = 0; b < 4; b++) acc[a][b] = (f32x4){0.f, 0.f, 0.f, 0.f};

  int rowb[4]; bool ract[4];
#pragma unroll
  for (int rf = 0; rf < 4; rf++) {
    rowb[rf] = (rf * 4 + wave) * 16;
    ract[rf] = rowb[rf] < n_e;
  }

  const int bj = tid >> 2, bq = tid & 3;
  const float* bsrc = w2 + ((size_t)e * DMODEL + nt * 64 + bj) * FDIM + bq * 16;
  const int arow = lane >> 3;
  const int achk = (lane & 7) ^ (arow & 7);
  const bf16* abase = H + (size_t)e * CAP * FDIM
                      + (size_t)arow * FDIM + achk * 8;

  for (int k0 = 0; k0 < FDIM; k0 += 64) {
    for (int i = wave; i * 8 < M_act; i += 4)
      g2lds16(abase + (size_t)i * 8 * FDIM + k0, &As[i * 512]);
    {
      const float* s = bsrc + k0;
      float4 f0 = *(const float4*)(s);
      float4 f1 = *(const float4*)(s + 4);
      float4 f2 = *(const float4*)(s + 8);
      float4 f3 = *(const float4*)(s + 12);
      union { bf16 h[16]; uint4 u[2]; } pk;
      pk.h[0]=(bf16)f0.x; pk.h[1]=(bf16)f0.y; pk.h[2]=(bf16)f0.z; pk.h[3]=(bf16)f0.w;
      pk.h[4]=(bf16)f1.x; pk.h[5]=(bf16)f1.y; pk.h[6]=(bf16)f1.z; pk.h[7]=(bf16)f1.w;
      pk.h[8]=(bf16)f2.x; pk.h[9]=(bf16)f2.y; pk.h[10]=(bf16)f2.z; pk.h[11]=(bf16)f2.w;
      pk.h[12]=(bf16)f3.x; pk.h[13]=(bf16)f3.y; pk.h[14]=(bf16)f3.z; pk.h[15]=(bf16)f3.w;
      const int c0 = (bq * 2) ^ (bj & 7);
      const int c1 = (bq * 2 + 1) ^ (bj & 7);
      *(uint4*)&Bs[bj * 64 + c0 * 8] = pk.u[0];
      *(uint4*)&Bs[bj * 64 + c1 * 8] = pk.u[1];
    }
    __syncthreads();
#pragma unroll
    for (int ks = 0; ks < 2; ks++) {
      const int sw = ((ks * 4 + lq) ^ (lm & 7)) * 8;
      bf16x8 bfr[4];
#pragma unroll
      for (int cf = 0; cf < 4; cf++)
        bfr[cf] = *(const bf16x8*)&Bs[(cf * 16 + lm) * 64 + sw];
#pragma unroll
      for (int rf = 0; rf < 4; rf++) {
        if (ract[rf]) {
          bf16x8 afr = *(const bf16x8*)&As[(rowb[rf] + lm) * 64 + sw];
#pragma unroll
          for (int cf = 0; cf < 4; cf++)
            acc[rf][cf] = __builtin_amdgcn_mfma_f32_16x16x32_bf16(
                afr, bfr[cf], acc[rf][cf], 0, 0, 0);
        }
      }
    }
    __syncthreads();
  }

  // epilogue: weighted scatter-add into out
#pragma unroll
  for (int rf = 0; rf < 4; rf++) {
    if (!ract[rf]) continue;
#pragma unroll
    for (int i = 0; i < 4; i++) {
      const int r = rowb[rf] + lq * 4 + i;
      if (r < n_e) {
        const int tok = ltok[e * CAP + r];
        const float cw = lwt[e * CAP + r];
        float* orow = out + (size_t)tok * DMODEL + nt * 64 + lm;
#pragma unroll
        for (int cf = 0; cf < 4; cf++)
          atomicAdd(orow + cf * 16, cw * acc[rf][cf][i]);
      }
    }
  }
}

// ---------------------------------------------------------------------------
extern "C" void kernel_launch(void* const* d_in, const int* in_sizes, int n_in,
                              void* d_out, int out_size, void* d_ws, size_t ws_size,
                              hipStream_t stream) {
  const float* x      = (const float*)d_in[0];   // [1024, 2048]
  const float* gate_w = (const float*)d_in[1];   // [64, 2048]
  const float* w13    = (const float*)d_in[2];   // [64, 1536, 2048]
  const float* w2     = (const float*)d_in[3];   // [64, 2048, 768]
  float* out = (float*)d_out;

  char* ws = (char*)d_ws;
  int*   cnt  = (int*)ws;                                   // 256 B
  int*   ltok = (int*)(ws + 1024);                          // 64 KB
  float* lwt  = (float*)(ws + 1024 + 65536);                // 64 KB
  bf16*  Xg   = (bf16*)(ws + 1024 + 2 * 65536);             // 64 MB
  bf16*  H    = (bf16*)(ws + 1024 + 2 * 65536
                        + (size_t)NEXP * CAP * DMODEL * sizeof(bf16)); // 24 MB

  hipMemsetAsync(d_out, 0, (size_t)out_size * sizeof(float), stream);
  hipMemsetAsync(cnt, 0, NEXP * sizeof(int), stream);

  router_kernel<<<TOKENS, 256, 0, stream>>>(x, gate_w, cnt, ltok, lwt);
  gather_kernel<<<dim3(CAP / 32, NEXP), 256, 0, stream>>>(x, cnt, ltok, Xg);
  gemm1_kernel<<<dim3(FDIM / 32, NEXP), 256, 0, stream>>>(w13, Xg, cnt, H);
  gemm2_kernel<<<dim3(DMODEL / 64, NEXP), 256, 0, stream>>>(w2, H, cnt, ltok, lwt, out);
}